// Round 1
// baseline (12162.016 us; speedup 1.0000x reference)
//
#include <hip/hip_runtime.h>
#include <hip/hip_bf16.h>

#define VOCAB  128
#define EMBED  256
#define HIDDEN 1024
#define SEQ    512
#define BATCH  128
#define NGCOL  4096   // 4*HIDDEN, gate-interleaved packed columns (p = 4*j + g)
#define NCOL   4224   // NGCOL + VOCAB (classifier columns appended)

typedef short s8v  __attribute__((ext_vector_type(8)));  // 8 bf16 in 4 VGPRs
typedef float f4   __attribute__((ext_vector_type(4)));

__device__ __forceinline__ unsigned short f2bf(float f) {
    unsigned u = __float_as_uint(f);
    u += 0x7fffu + ((u >> 16) & 1u);   // round-to-nearest-even
    return (unsigned short)(u >> 16);
}
__device__ __forceinline__ float sigm(float x) { return 1.f / (1.f + __expf(-x)); }
__device__ __forceinline__ float tanh_(float x) {
    x = fminf(fmaxf(x, -15.f), 15.f);
    float e = __expf(2.f * x);
    return (e - 1.f) / (e + 1.f);
}

// ---- Pack W_h (4 gates, interleaved) + W_cls into bf16 fragment-friendly layout ----
// Bp element offset for (packed col p, k): ((p/16)*128 + k/8)*128 + (p%16)*8 + (k%8)
// so a B-fragment load (lane: col=lane%16, k0=(lane/16)*8) is one contiguous 16B load.
__global__ void k_pack(const float* __restrict__ Wi, const float* __restrict__ Wf,
                       const float* __restrict__ Wg, const float* __restrict__ Wo,
                       const float* __restrict__ Wcls, unsigned short* __restrict__ Bp) {
    int idx = blockIdx.x * 256 + threadIdx.x;
    if (idx >= NCOL * HIDDEN) return;
    int p = idx / HIDDEN, k = idx % HIDDEN;
    float v;
    if (p < NGCOL) {
        int g = p & 3, j = p >> 2;
        const float* W = (g == 0) ? Wi : (g == 1) ? Wf : (g == 2) ? Wg : Wo;
        v = W[k * HIDDEN + j];                 // W_h is [k][j] row-major
    } else {
        v = Wcls[(p - NGCOL) * HIDDEN + k];    // W_cls is [v][k]; B[k][col=v] = W_cls[v][k]
    }
    Bp[((p >> 4) * 128 + (k >> 3)) * 128 + (p & 15) * 8 + (k & 7)] = f2bf(v);
}

// ---- proj[v][p] = b_g[j] + sum_e emb[v][e] * W_gx[e][j]  (p = 4j+g), f32 ----
__global__ void k_proj(const float* __restrict__ emb,
                       const float* __restrict__ Wix, const float* __restrict__ Wfx,
                       const float* __restrict__ Wgx, const float* __restrict__ Wox,
                       const float* __restrict__ bi,  const float* __restrict__ bf_,
                       const float* __restrict__ bg,  const float* __restrict__ bo,
                       float* __restrict__ proj) {
    int idx = blockIdx.x * 256 + threadIdx.x;
    if (idx >= VOCAB * NGCOL) return;
    int v = idx / NGCOL, p = idx % NGCOL;
    int g = p & 3, j = p >> 2;
    const float* W = (g == 0) ? Wix : (g == 1) ? Wfx : (g == 2) ? Wgx : Wox;
    const float* b = (g == 0) ? bi  : (g == 1) ? bf_ : (g == 2) ? bg  : bo;
    float s = b[j];
    const float* er = emb + v * EMBED;
    #pragma unroll 4
    for (int e = 0; e < EMBED; ++e) s += er[e] * W[e * HIDDEN + j];
    proj[idx] = s;
}

// ---- One timestep: gates = proj[x_t] + h_prev @ Wh_packed ; also logits[s-1] = h_prev @ Wcls^T + b ----
// Grid: 264 blocks = 2 row-tiles(64) x 132 col-tiles(32). Block: 256 thr = 4 waves (2x2),
// wave tile = 32 rows x 16 cols, mfma_f32_16x16x32_bf16, K=1024.
__global__ __launch_bounds__(256) void k_step(
        const unsigned short* __restrict__ hprev, unsigned short* __restrict__ hnext,
        float* __restrict__ c, const float* __restrict__ proj,
        const unsigned short* __restrict__ Bp, const int* __restrict__ x,
        float* __restrict__ out, const float* __restrict__ bcls, int s) {
    int bx = blockIdx.x;
    int nt = bx >> 1, mt = bx & 1;
    bool isLogit = (nt >= 128);
    if (isLogit && s == 0) return;      // no h yet
    if (!isLogit && s == SEQ) return;   // final launch: logits only

    int tid = threadIdx.x;
    int wave = tid >> 6, lane = tid & 63;
    int wm = wave >> 1, wn = wave & 1;
    int rowbase = mt * 64 + wm * 32;
    int p0 = nt * 32 + wn * 16;
    int l16 = lane & 15, lhi = lane >> 4;

    f4 acc0 = {0.f, 0.f, 0.f, 0.f}, acc1 = {0.f, 0.f, 0.f, 0.f};
    const unsigned short* abase0 = hprev + (rowbase + l16) * HIDDEN + lhi * 8;
    const unsigned short* abase1 = abase0 + 16 * HIDDEN;
    const unsigned short* bbase  = Bp + ((p0 >> 4) * 128 + lhi) * 128 + l16 * 8;

    #pragma unroll 8
    for (int kb = 0; kb < HIDDEN; kb += 32) {
        s8v a0 = *(const s8v*)(abase0 + kb);
        s8v a1 = *(const s8v*)(abase1 + kb);
        s8v b  = *(const s8v*)(bbase + kb * 16);   // kgrp advances 4 per 32 k
        acc0 = __builtin_amdgcn_mfma_f32_16x16x32_bf16(a0, b, acc0, 0, 0, 0);
        acc1 = __builtin_amdgcn_mfma_f32_16x16x32_bf16(a1, b, acc1, 0, 0, 0);
    }

    int p = p0 + l16;   // global packed column for this lane
    if (!isLogit) {
        const int* xs = x + s * BATCH;
        #pragma unroll
        for (int a = 0; a < 2; ++a) {
            f4 acc = a ? acc1 : acc0;
            int rb = rowbase + a * 16 + lhi * 4;
            #pragma unroll
            for (int r = 0; r < 4; ++r) {
                int row = rb + r;
                float pre = acc[r] + proj[xs[row] * NGCOL + p];
                int qb = lane & ~3;
                float xi = __shfl(pre, qb | 0);
                float xf = __shfl(pre, qb | 1);
                float xg = __shfl(pre, qb | 2);
                float xo = __shfl(pre, qb | 3);
                if ((lane & 3) == 0) {
                    int j = p >> 2;
                    int idx = row * HIDDEN + j;
                    float i_ = sigm(xi), f_ = sigm(xf), g_ = tanh_(xg), o_ = sigm(xo);
                    float cn = f_ * c[idx] + i_ * g_;
                    c[idx] = cn;
                    hnext[idx] = f2bf(o_ * tanh_(cn));
                }
            }
        }
    } else {
        int v = p - NGCOL;
        float bb = bcls[v];
        float* ob = out + (size_t)(s - 1) * BATCH * VOCAB;
        #pragma unroll
        for (int a = 0; a < 2; ++a) {
            f4 acc = a ? acc1 : acc0;
            int rb = rowbase + a * 16 + lhi * 4;
            #pragma unroll
            for (int r = 0; r < 4; ++r)
                ob[(rb + r) * VOCAB + v] = acc[r] + bb;
        }
    }
}

extern "C" void kernel_launch(void* const* d_in, const int* in_sizes, int n_in,
                              void* d_out, int out_size, void* d_ws, size_t ws_size,
                              hipStream_t stream) {
    const int*   x    = (const int*)d_in[0];
    const float* emb  = (const float*)d_in[1];
    const float* Wix  = (const float*)d_in[2];
    const float* Wih  = (const float*)d_in[3];
    const float* bi   = (const float*)d_in[4];
    const float* Wfx  = (const float*)d_in[5];
    const float* Wfh  = (const float*)d_in[6];
    const float* bf   = (const float*)d_in[7];
    const float* Wgx  = (const float*)d_in[8];
    const float* Wgh  = (const float*)d_in[9];
    const float* bg   = (const float*)d_in[10];
    const float* Wox  = (const float*)d_in[11];
    const float* Woh  = (const float*)d_in[12];
    const float* bo   = (const float*)d_in[13];
    const float* Wcls = (const float*)d_in[14];
    const float* bcls = (const float*)d_in[15];
    float* out = (float*)d_out;

    char* ws = (char*)d_ws;
    float*          c    = (float*)ws;                          // 512 KB
    unsigned short* hb0  = (unsigned short*)(ws + (512 << 10)); // 256 KB
    unsigned short* hb1  = (unsigned short*)(ws + (768 << 10)); // 256 KB
    float*          proj = (float*)(ws + (1024 << 10));         // 2 MB
    unsigned short* Bp   = (unsigned short*)(ws + (3072 << 10));// 8.65 MB

    // zero c and h0 (hb1 is fully written by step 0 before any read)
    hipMemsetAsync(ws, 0, 1024 << 10, stream);

    k_pack<<<(NCOL * HIDDEN + 255) / 256, 256, 0, stream>>>(Wih, Wfh, Wgh, Woh, Wcls, Bp);
    k_proj<<<(VOCAB * NGCOL + 255) / 256, 256, 0, stream>>>(emb, Wix, Wfx, Wgx, Wox,
                                                            bi, bf, bg, bo, proj);
    for (int s = 0; s <= SEQ; ++s) {
        const unsigned short* hp = (s & 1) ? hb1 : hb0;
        unsigned short*       hn = (s & 1) ? hb0 : hb1;
        k_step<<<264, 256, 0, stream>>>(hp, hn, c, proj, Bp, x, out, bcls, s);
    }
}